// Round 18
// baseline (485.225 us; speedup 1.0000x reference)
//
#include <hip/hip_runtime.h>

typedef __attribute__((ext_vector_type(8))) short short8v;
typedef __attribute__((ext_vector_type(4))) float float4v;
typedef __attribute__((ext_vector_type(2))) float float2v;

__device__ __forceinline__ ushort f2bf(float f) {
  union { float f; unsigned u; } v; v.f = f;
  unsigned r = v.u + 0x7fffu + ((v.u >> 16) & 1u);  // RNE
  return (ushort)(r >> 16);
}
__device__ __forceinline__ float bf2f(ushort h) {
  union { unsigned u; float f; } v; v.u = ((unsigned)h) << 16;
  return v.f;
}
__device__ __forceinline__ float ubf(unsigned u, int hi) {
  return __uint_as_float(hi ? (u & 0xFFFF0000u) : (u << 16));
}

// ---------------- CSR build (incoming edges per dst, self-loop appended) ----------------
__global__ void count_part(const int* __restrict__ dstp, int* __restrict__ cnt,
                           int E, int N, int nblk) {
  int grp = blockIdx.x & 7;
  int gb = blockIdx.x >> 3;
  int gn = nblk >> 3;
  int lo = (int)(((long long)N * grp) >> 3);
  int hi = (int)(((long long)N * (grp + 1)) >> 3);
  for (int e = gb * blockDim.x + threadIdx.x; e < E; e += gn * blockDim.x) {
    int d = dstp[e];
    if (d >= lo && d < hi) atomicAdd(&cnt[d], 1);
  }
}

__global__ void fill_part(const int* __restrict__ srcp, const int* __restrict__ dstp,
                          const int* __restrict__ rowptr, int* __restrict__ cur,
                          int* __restrict__ csr_src, int E, int N, int nblk) {
  int grp = blockIdx.x & 7;
  int gb = blockIdx.x >> 3;
  int gn = nblk >> 3;
  int lo = (int)(((long long)N * grp) >> 3);
  int hi = (int)(((long long)N * (grp + 1)) >> 3);
  for (int e = gb * blockDim.x + threadIdx.x; e < E; e += gn * blockDim.x) {
    int d = dstp[e];
    if (d >= lo && d < hi) {
      int pos = atomicAdd(&cur[d], 1);
      csr_src[rowptr[d] + pos] = srcp[e] << 7;   // pre-scaled element offset
    }
  }
}

__global__ __launch_bounds__(1024)
void scan_blocks(const int* __restrict__ cnt, int* __restrict__ tscan,
                 int* __restrict__ bsum, int n) {
  __shared__ int sh[1024];
  int t = threadIdx.x;
  int i = blockIdx.x * 1024 + t;
  sh[t] = (i < n) ? cnt[i] + 1 : 0;
  __syncthreads();
  for (int off = 1; off < 1024; off <<= 1) {
    int u = (t >= off) ? sh[t - off] : 0;
    __syncthreads();
    sh[t] += u;
    __syncthreads();
  }
  if (i < n) tscan[i] = sh[t];
  if (t == 1023) bsum[blockIdx.x] = sh[1023];
}

__global__ __launch_bounds__(1024)
void scan_final(int* __restrict__ cnt, const int* __restrict__ tscan,
                const int* __restrict__ bsum, int* __restrict__ rowptr,
                int* __restrict__ csr_src, int n, int nb) {
  __shared__ int sh[1024];
  int t = threadIdx.x;
  sh[t] = (t < nb) ? bsum[t] : 0;
  __syncthreads();
  for (int off = 1; off < 1024; off <<= 1) {
    int u = (t >= off) ? sh[t - off] : 0;
    __syncthreads();
    sh[t] += u;
    __syncthreads();
  }
  int i = blockIdx.x * 1024 + t;
  if (i < n) {
    int bpref = (blockIdx.x == 0) ? 0 : sh[blockIdx.x - 1];
    int incl = bpref + tscan[i];
    rowptr[i] = incl - (cnt[i] + 1);
    csr_src[incl - 1] = i << 7;           // self-loop (pre-scaled)
    cnt[i] = 0;                           // becomes `cur` for fill_part
  }
  if (blockIdx.x == nb - 1 && t == 0) rowptr[n] = sh[nb - 1];
}

// ---------------- fused weight-pack + x-cast (one launch) ----------------
struct PackArgs {
  const float* w[8];
  ushort* o[8];
  int nout[8];
};
__global__ __launch_bounds__(256)
void pack_split(PackArgs pa, const float* __restrict__ x,
                ushort* __restrict__ xhi, int nx) {
  if (blockIdx.x < 64) {
    int wsel = blockIdx.x >> 3;
    int sub = blockIdx.x & 7;
    const float* W = pa.w[wsel];
    ushort* pk = pa.o[wsel];
    int NOUT = pa.nout[wsel];
    int NT = NOUT / 16;
    int total = NT * 4 * 64;
    int t = sub * 256 + threadIdx.x;
    if (t >= total) return;
    int lane = t & 63;
    int ks = (t >> 6) & 3;
    int nt = t >> 8;
    int col = nt * 16 + (lane & 15);
    int k0 = ks * 32 + (lane >> 4) * 8;
    ushort h[8], l[8];
#pragma unroll
    for (int j = 0; j < 8; ++j) {
      float v = W[(size_t)(k0 + j) * NOUT + col];
      h[j] = f2bf(v);
      l[j] = f2bf(v - bf2f(h[j]));
    }
    size_t fb = ((size_t)(nt * 4 + ks) * 64 + lane) * 8;
    size_t fragsz = (size_t)total * 8;
#pragma unroll
    for (int j = 0; j < 8; ++j) { pk[fb + j] = h[j]; pk[fragsz + fb + j] = l[j]; }
  } else {
    int i = ((blockIdx.x - 64) * 256 + threadIdx.x) * 4;
    if (i >= nx) return;
    float4 v = *(const float4*)(x + i);
    *(ushort4*)(xhi + i) = make_ushort4(f2bf(v.x), f2bf(v.y), f2bf(v.z), f2bf(v.w));
  }
}

// ---------- Fused triple MFMA GEMM, 2 row-tiles/block: Cp = Ah @ (Whi+Wlo) + bp ----------
// Each block handles 128 rows (two 64-row tiles). W fragments are loaded ONCE
// per ks and reused for both tiles: halves the W-load:MFMA ratio (the K-loop
// was W-latency-bound) and halves grid-level W re-streaming.
__global__ __launch_bounds__(512)
void gemm3_mfma(const ushort* __restrict__ Ah,
                const ushort* __restrict__ W0, const ushort* __restrict__ W1,
                const ushort* __restrict__ W2,
                const float* __restrict__ b0, const float* __restrict__ b1,
                const float* __restrict__ b2,
                ushort* __restrict__ C0b, ushort* __restrict__ C1b,
                ushort* __restrict__ C2b, int M) {
  int tid = threadIdx.x;
  int w = tid >> 6, lane = tid & 63;
  int l15 = lane & 15, lh = lane >> 4;
  int row0 = blockIdx.x * 128;

  const ushort* Wp[3] = {W0, W1, W2};

  int arow[2][4];
#pragma unroll
  for (int t2 = 0; t2 < 2; ++t2)
#pragma unroll
    for (int mt = 0; mt < 4; ++mt) {
      int rr = row0 + t2 * 64 + mt * 16 + l15;
      arow[t2][mt] = rr < M ? rr : M - 1;
    }

  float4v acc[3][2][4];
#pragma unroll
  for (int p = 0; p < 3; ++p)
#pragma unroll
    for (int t2 = 0; t2 < 2; ++t2)
#pragma unroll
      for (int mt = 0; mt < 4; ++mt) {
        acc[p][t2][mt][0] = 0.f; acc[p][t2][mt][1] = 0.f;
        acc[p][t2][mt][2] = 0.f; acc[p][t2][mt][3] = 0.f;
      }

  const size_t fragsz = (size_t)8 * 4 * 64 * 8;  // NT=8
#pragma unroll 1
  for (int ks = 0; ks < 4; ++ks) {
    short8v bh[3], bl[3];
    size_t fb = ((size_t)(w * 4 + ks) * 64 + lane) * 8;
#pragma unroll
    for (int p = 0; p < 3; ++p) {
      bh[p] = *(const short8v*)(Wp[p] + fb);
      bl[p] = *(const short8v*)(Wp[p] + fragsz + fb);
    }
#pragma unroll
    for (int t2 = 0; t2 < 2; ++t2) {
#pragma unroll
      for (int mt = 0; mt < 4; ++mt) {
        size_t ao = (size_t)arow[t2][mt] * 128 + ks * 32 + lh * 8;
        short8v ah = *(const short8v*)(Ah + ao);
#pragma unroll
        for (int p = 0; p < 3; ++p) {
          acc[p][t2][mt] = __builtin_amdgcn_mfma_f32_16x16x32_bf16(ah, bh[p], acc[p][t2][mt], 0, 0, 0);
          acc[p][t2][mt] = __builtin_amdgcn_mfma_f32_16x16x32_bf16(ah, bl[p], acc[p][t2][mt], 0, 0, 0);
        }
      }
    }
  }

  int col = w * 16 + l15;
  float bb0 = b0[col], bb1 = b1[col], bb2 = b2[col];
#pragma unroll
  for (int t2 = 0; t2 < 2; ++t2) {
#pragma unroll
    for (int mt = 0; mt < 4; ++mt) {
#pragma unroll
      for (int r = 0; r < 4; ++r) {
        int rr = row0 + t2 * 64 + mt * 16 + lh * 4 + r;
        if (rr < M) {
          C0b[(size_t)rr * 128 + col] = f2bf(acc[0][t2][mt][r] + bb0);
          C1b[(size_t)rr * 128 + col] = f2bf(acc[1][t2][mt][r] + bb1);
          C2b[(size_t)rr * 128 + col] = f2bf(acc[2][t2][mt][r] + bb2);
        }
      }
    }
  }
}

// ---------- Fused MLP head: out = relu(Ah@W1+b1) @ W2 + b2 ----------
__global__ __launch_bounds__(256)
void mlp_fused(const ushort* __restrict__ Ah,
               const ushort* __restrict__ W1pk, const float* __restrict__ b1,
               const ushort* __restrict__ W2pk, const float* __restrict__ b2,
               float* __restrict__ out, int M) {
  __shared__ ushort m1[2][16][64][8];   // [hi/lo][k>>3][row][k&7]
  int tid = threadIdx.x;
  int w = tid >> 6, lane = tid & 63;
  int l15 = lane & 15, lh = lane >> 4;
  int row0 = blockIdx.x * 64;

  int arow[4];
#pragma unroll
  for (int mt = 0; mt < 4; ++mt) { int rr = row0 + mt * 16 + l15; arow[mt] = rr < M ? rr : M - 1; }

  float4v acc1[4][2];
#pragma unroll
  for (int mt = 0; mt < 4; ++mt)
#pragma unroll
    for (int j = 0; j < 2; ++j) {
      acc1[mt][j][0] = 0.f; acc1[mt][j][1] = 0.f; acc1[mt][j][2] = 0.f; acc1[mt][j][3] = 0.f;
    }
  const size_t fragsz1 = (size_t)8 * 4 * 64 * 8;
#pragma unroll 2
  for (int ks = 0; ks < 4; ++ks) {
    short8v bh[2], bl[2];
#pragma unroll
    for (int nt2 = 0; nt2 < 2; ++nt2) {
      size_t fb = ((size_t)((w * 2 + nt2) * 4 + ks) * 64 + lane) * 8;
      bh[nt2] = *(const short8v*)(W1pk + fb);
      bl[nt2] = *(const short8v*)(W1pk + fragsz1 + fb);
    }
#pragma unroll
    for (int mt = 0; mt < 4; ++mt) {
      size_t ao = (size_t)arow[mt] * 128 + ks * 32 + lh * 8;
      short8v ah = *(const short8v*)(Ah + ao);
#pragma unroll
      for (int nt2 = 0; nt2 < 2; ++nt2) {
        acc1[mt][nt2] = __builtin_amdgcn_mfma_f32_16x16x32_bf16(ah, bh[nt2], acc1[mt][nt2], 0, 0, 0);
        acc1[mt][nt2] = __builtin_amdgcn_mfma_f32_16x16x32_bf16(ah, bl[nt2], acc1[mt][nt2], 0, 0, 0);
      }
    }
  }
#pragma unroll
  for (int nt2 = 0; nt2 < 2; ++nt2) {
    int col = (w * 2 + nt2) * 16 + l15;
    float bb = b1[col];
    int kf = col >> 3, kr = col & 7;
#pragma unroll
    for (int mt = 0; mt < 4; ++mt) {
#pragma unroll
      for (int r = 0; r < 4; ++r) {
        int row = mt * 16 + lh * 4 + r;
        float v = fmaxf(acc1[mt][nt2][r] + bb, 0.f);
        ushort h = f2bf(v);
        m1[0][kf][row][kr] = h;
        m1[1][kf][row][kr] = f2bf(v - bf2f(h));
      }
    }
  }
  __syncthreads();

  float4v acc2[4];
#pragma unroll
  for (int mt = 0; mt < 4; ++mt) {
    acc2[mt][0] = 0.f; acc2[mt][1] = 0.f; acc2[mt][2] = 0.f; acc2[mt][3] = 0.f;
  }
  const size_t fragsz2 = (size_t)4 * 4 * 64 * 8;
#pragma unroll 2
  for (int ks = 0; ks < 4; ++ks) {
    size_t fb = ((size_t)(w * 4 + ks) * 64 + lane) * 8;
    short8v bh = *(const short8v*)(W2pk + fb);
    short8v bl = *(const short8v*)(W2pk + fragsz2 + fb);
#pragma unroll
    for (int mt = 0; mt < 4; ++mt) {
      int row = mt * 16 + l15;
      short8v ah = *(const short8v*)&m1[0][ks * 4 + lh][row][0];
      short8v al = *(const short8v*)&m1[1][ks * 4 + lh][row][0];
      acc2[mt] = __builtin_amdgcn_mfma_f32_16x16x32_bf16(ah, bh, acc2[mt], 0, 0, 0);
      acc2[mt] = __builtin_amdgcn_mfma_f32_16x16x32_bf16(ah, bl, acc2[mt], 0, 0, 0);
      acc2[mt] = __builtin_amdgcn_mfma_f32_16x16x32_bf16(al, bh, acc2[mt], 0, 0, 0);
    }
  }
  int col = w * 16 + l15;
  float bb = b2[col];
#pragma unroll
  for (int mt = 0; mt < 4; ++mt) {
#pragma unroll
    for (int r = 0; r < 4; ++r) {
      int rr = row0 + mt * 16 + lh * 4 + r;
      if (rr < M) out[(size_t)rr * 64 + col] = acc2[mt][r] + bb;
    }
  }
}

// ---------- GATv2 aggregation: pk-fp32, 4 edges/half (r16 structure) ----------
template<int H>
__global__ __launch_bounds__(256)
void gat_agg(const ushort* __restrict__ xlb, const ushort* __restrict__ xrb,
             const ushort* __restrict__ skb, const float* __restrict__ att,
             const float* __restrict__ gbias, const int* __restrict__ rowptr,
             const int* __restrict__ csr_src, ushort* __restrict__ outhi,
             int n, int relu) {
  constexpr int GL = (128 / H) / 4;  // lanes per head group: H=4 -> 8, H=1 -> 32
  int wid = blockIdx.x * (blockDim.x >> 6) + (threadIdx.x >> 6);
  if (wid >= n) return;
  int lane = threadIdx.x & 63;
  int half = lane >> 5;
  int sub = lane & 31;
  size_t base = (size_t)wid * 128 + sub * 4;
  const ushort* xl_l = xlb + sub * 4;   // per-lane base; gather = xl_l + off
  uint2 ur = *(const uint2*)(xrb + base);
  float2v xr01 = {ubf(ur.x, 0), ubf(ur.x, 1)};
  float2v xr23 = {ubf(ur.y, 0), ubf(ur.y, 1)};
  float4 avf = *(const float4*)(att + sub * 4);
  float2v av01 = {avf.x, avf.y};
  float2v av23 = {avf.z, avf.w};
  float2v acc01 = {0.f, 0.f}, acc23 = {0.f, 0.f};
  float denom = 0.f;
  int e0 = rowptr[wid], e1 = rowptr[wid + 1];

  int idx = e0 + half;
  for (; idx + 6 < e1; idx += 8) {
    int o0 = csr_src[idx], o1 = csr_src[idx + 2], o2 = csr_src[idx + 4], o3 = csr_src[idx + 6];
    uint2 u0 = *(const uint2*)(xl_l + o0);
    uint2 u1 = *(const uint2*)(xl_l + o1);
    uint2 u2 = *(const uint2*)(xl_l + o2);
    uint2 u3 = *(const uint2*)(xl_l + o3);
    float2v a01 = {ubf(u0.x, 0), ubf(u0.x, 1)}, a23 = {ubf(u0.y, 0), ubf(u0.y, 1)};
    float2v b01 = {ubf(u1.x, 0), ubf(u1.x, 1)}, b23 = {ubf(u1.y, 0), ubf(u1.y, 1)};
    float2v c01 = {ubf(u2.x, 0), ubf(u2.x, 1)}, c23 = {ubf(u2.y, 0), ubf(u2.y, 1)};
    float2v d01 = {ubf(u3.x, 0), ubf(u3.x, 1)}, d23 = {ubf(u3.y, 0), ubf(u3.y, 1)};
    float2v t01, t23, l01, l23, pp;
    t01 = a01 + xr01; t23 = a23 + xr23;
    l01 = __builtin_elementwise_max(t01, t01 * 0.2f);
    l23 = __builtin_elementwise_max(t23, t23 * 0.2f);
    pp = __builtin_elementwise_fma(l23, av23, l01 * av01);
    float p0 = pp[0] + pp[1];
    t01 = b01 + xr01; t23 = b23 + xr23;
    l01 = __builtin_elementwise_max(t01, t01 * 0.2f);
    l23 = __builtin_elementwise_max(t23, t23 * 0.2f);
    pp = __builtin_elementwise_fma(l23, av23, l01 * av01);
    float p1 = pp[0] + pp[1];
    t01 = c01 + xr01; t23 = c23 + xr23;
    l01 = __builtin_elementwise_max(t01, t01 * 0.2f);
    l23 = __builtin_elementwise_max(t23, t23 * 0.2f);
    pp = __builtin_elementwise_fma(l23, av23, l01 * av01);
    float p2 = pp[0] + pp[1];
    t01 = d01 + xr01; t23 = d23 + xr23;
    l01 = __builtin_elementwise_max(t01, t01 * 0.2f);
    l23 = __builtin_elementwise_max(t23, t23 * 0.2f);
    pp = __builtin_elementwise_fma(l23, av23, l01 * av01);
    float p3 = pp[0] + pp[1];
#pragma unroll
    for (int o = 1; o < GL; o <<= 1) {
      p0 += __shfl_xor(p0, o, 64);
      p1 += __shfl_xor(p1, o, 64);
      p2 += __shfl_xor(p2, o, 64);
      p3 += __shfl_xor(p3, o, 64);
    }
    float w0 = __expf(p0), w1 = __expf(p1), w2 = __expf(p2), w3 = __expf(p3);
    denom += (w0 + w1) + (w2 + w3);
    float2v w0v = {w0, w0}, w1v = {w1, w1}, w2v = {w2, w2}, w3v = {w3, w3};
    acc01 = __builtin_elementwise_fma(w0v, a01, acc01);
    acc23 = __builtin_elementwise_fma(w0v, a23, acc23);
    acc01 = __builtin_elementwise_fma(w1v, b01, acc01);
    acc23 = __builtin_elementwise_fma(w1v, b23, acc23);
    acc01 = __builtin_elementwise_fma(w2v, c01, acc01);
    acc23 = __builtin_elementwise_fma(w2v, c23, acc23);
    acc01 = __builtin_elementwise_fma(w3v, d01, acc01);
    acc23 = __builtin_elementwise_fma(w3v, d23, acc23);
  }
  for (; idx < e1; idx += 2) {
    int o0 = csr_src[idx];
    uint2 u0 = *(const uint2*)(xl_l + o0);
    float2v a01 = {ubf(u0.x, 0), ubf(u0.x, 1)}, a23 = {ubf(u0.y, 0), ubf(u0.y, 1)};
    float2v t01 = a01 + xr01, t23 = a23 + xr23;
    float2v l01 = __builtin_elementwise_max(t01, t01 * 0.2f);
    float2v l23 = __builtin_elementwise_max(t23, t23 * 0.2f);
    float2v pp = __builtin_elementwise_fma(l23, av23, l01 * av01);
    float p0 = pp[0] + pp[1];
#pragma unroll
    for (int o = 1; o < GL; o <<= 1) p0 += __shfl_xor(p0, o, 64);
    float w0 = __expf(p0);
    denom += w0;
    float2v w0v = {w0, w0};
    acc01 = __builtin_elementwise_fma(w0v, a01, acc01);
    acc23 = __builtin_elementwise_fma(w0v, a23, acc23);
  }

  float ax = acc01[0], ay = acc01[1], az = acc23[0], aw = acc23[1];
  ax += __shfl_xor(ax, 32, 64);
  ay += __shfl_xor(ay, 32, 64);
  az += __shfl_xor(az, 32, 64);
  aw += __shfl_xor(aw, 32, 64);
  denom += __shfl_xor(denom, 32, 64);

  if (half == 0) {
    float inv = 1.f / denom;
    uint2 us = *(const uint2*)(skb + base);
    float4 sk;
    sk.x = ubf(us.x, 0); sk.y = ubf(us.x, 1);
    sk.z = ubf(us.y, 0); sk.w = ubf(us.y, 1);
    float4 gb = *(const float4*)(gbias + sub * 4);
    float o0 = ax * inv + gb.x + sk.x;
    float o1 = ay * inv + gb.y + sk.y;
    float o2 = az * inv + gb.z + sk.z;
    float o3 = aw * inv + gb.w + sk.w;
    if (relu) {
      o0 = fmaxf(o0, 0.f); o1 = fmaxf(o1, 0.f);
      o2 = fmaxf(o2, 0.f); o3 = fmaxf(o3, 0.f);
    }
    *(ushort4*)(outhi + base) = make_ushort4(f2bf(o0), f2bf(o1), f2bf(o2), f2bf(o3));
  }
}

extern "C" void kernel_launch(void* const* d_in, const int* in_sizes, int n_in,
                              void* d_out, int out_size, void* d_ws, size_t ws_size,
                              hipStream_t stream) {
  const float* x       = (const float*)d_in[0];
  const int* ei        = (const int*)d_in[1];
  const float* Wl1     = (const float*)d_in[2];
  const float* bl1     = (const float*)d_in[3];
  const float* Wr1     = (const float*)d_in[4];
  const float* br1     = (const float*)d_in[5];
  const float* att1    = (const float*)d_in[6];
  const float* b1      = (const float*)d_in[7];
  const float* Wl2     = (const float*)d_in[8];
  const float* bl2     = (const float*)d_in[9];
  const float* Wr2     = (const float*)d_in[10];
  const float* br2     = (const float*)d_in[11];
  const float* att2    = (const float*)d_in[12];
  const float* b2      = (const float*)d_in[13];
  const float* skip1_w = (const float*)d_in[14];
  const float* skip1_b = (const float*)d_in[15];
  const float* skip2_w = (const float*)d_in[16];
  const float* skip2_b = (const float*)d_in[17];
  const float* mlp1_w  = (const float*)d_in[18];
  const float* mlp1_b  = (const float*)d_in[19];
  const float* mlp2_w  = (const float*)d_in[20];
  const float* mlp2_b  = (const float*)d_in[21];

  const int N = in_sizes[0] / 128;
  const int E = in_sizes[1] / 2;
  float* out = (float*)d_out;

  char* ws = (char*)d_ws;
  size_t off = 0;
  auto alloc = [&](size_t bytes) -> void* {
    void* p = ws + off;
    off = (off + bytes + 255) & ~(size_t)255;
    return p;
  };
  int* rowptr  = (int*)alloc((size_t)(N + 1) * sizeof(int));
  int* cnt     = (int*)alloc((size_t)N * sizeof(int));
  int* tscan   = (int*)alloc((size_t)N * sizeof(int));
  int* bsum    = (int*)alloc((size_t)1024 * sizeof(int));
  int* csr_src = (int*)alloc((size_t)(E + N) * sizeof(int));
  ushort* wpk[8];
  for (int i = 0; i < 8; ++i) wpk[i] = (ushort*)alloc(128 * 128 * 2 * sizeof(ushort));
  ushort* p0hi = (ushort*)alloc((size_t)N * 128 * sizeof(ushort));
  ushort* xlb  = (ushort*)alloc((size_t)N * 128 * sizeof(ushort));
  ushort* xrb  = (ushort*)alloc((size_t)N * 128 * sizeof(ushort));
  ushort* skb  = (ushort*)alloc((size_t)N * 128 * sizeof(ushort));

  const int* srcp = ei;
  const int* dstp = ei + E;

  const int ggrid2 = (N + 127) / 128;   // gemm3: 128 rows/block
  const int ggrid  = (N + 63) / 64;     // mlp: 64 rows/block
  const int agrid  = (N + 3) / 4;
  const int nb = (N + 1023) / 1024;
  const int PARTB = 2048;

  // CSR by dst with embedded self-loops (partitioned count/fill)
  hipMemsetAsync(cnt, 0, (size_t)N * sizeof(int), stream);
  count_part<<<PARTB, 256, 0, stream>>>(dstp, cnt, E, N, PARTB);
  scan_blocks<<<nb, 1024, 0, stream>>>(cnt, tscan, bsum, N);
  scan_final<<<nb, 1024, 0, stream>>>(cnt, tscan, bsum, rowptr, csr_src, N, nb);
  fill_part<<<PARTB, 256, 0, stream>>>(srcp, dstp, rowptr, cnt, csr_src, E, N, PARTB);

  // Weight packs + x bf16-cast (one fused launch)
  PackArgs pa;
  pa.w[0] = Wl1;    pa.o[0] = wpk[0]; pa.nout[0] = 128;
  pa.w[1] = Wr1;    pa.o[1] = wpk[1]; pa.nout[1] = 128;
  pa.w[2] = skip1_w;pa.o[2] = wpk[2]; pa.nout[2] = 128;
  pa.w[3] = Wl2;    pa.o[3] = wpk[3]; pa.nout[3] = 128;
  pa.w[4] = Wr2;    pa.o[4] = wpk[4]; pa.nout[4] = 128;
  pa.w[5] = skip2_w;pa.o[5] = wpk[5]; pa.nout[5] = 128;
  pa.w[6] = mlp1_w; pa.o[6] = wpk[6]; pa.nout[6] = 128;
  pa.w[7] = mlp2_w; pa.o[7] = wpk[7]; pa.nout[7] = 64;
  const int sgrid = 64 + (N * 128 / 4 + 255) / 256;
  pack_split<<<sgrid, 256, 0, stream>>>(pa, x, p0hi, N * 128);

  // ---- Layer 1: fused {xl1, xr1, skip1} GEMM, then agg ----
  gemm3_mfma<<<ggrid2, 512, 0, stream>>>(p0hi, wpk[0], wpk[1], wpk[2],
                                         bl1, br1, skip1_b, xlb, xrb, skb, N);
  gat_agg<4><<<agrid, 256, 0, stream>>>(xlb, xrb, skb, att1, b1,
                                        rowptr, csr_src, p0hi, N, 1);

  // ---- Layer 2: fused {xl2, xr2, skip2} GEMM, then agg ----
  gemm3_mfma<<<ggrid2, 512, 0, stream>>>(p0hi, wpk[3], wpk[4], wpk[5],
                                         bl2, br2, skip2_b, xlb, xrb, skb, N);
  gat_agg<1><<<agrid, 256, 0, stream>>>(xlb, xrb, skb, att2, b2,
                                        rowptr, csr_src, p0hi, N, 0);

  // ---- Fused MLP head ----
  mlp_fused<<<ggrid, 256, 0, stream>>>(p0hi, wpk[6], mlp1_b, wpk[7], mlp2_b, out, N);
}

// Round 19
// 462.109 us; speedup vs baseline: 1.0500x; 1.0500x over previous
//
#include <hip/hip_runtime.h>

typedef __attribute__((ext_vector_type(8))) short short8v;
typedef __attribute__((ext_vector_type(4))) float float4v;
typedef __attribute__((ext_vector_type(2))) float float2v;

__device__ __forceinline__ ushort f2bf(float f) {
  union { float f; unsigned u; } v; v.f = f;
  unsigned r = v.u + 0x7fffu + ((v.u >> 16) & 1u);  // RNE
  return (ushort)(r >> 16);
}
__device__ __forceinline__ float bf2f(ushort h) {
  union { unsigned u; float f; } v; v.u = ((unsigned)h) << 16;
  return v.f;
}
__device__ __forceinline__ float ubf(unsigned u, int hi) {
  return __uint_as_float(hi ? (u & 0xFFFF0000u) : (u << 16));
}

// ---------------- CSR build (incoming edges per dst, self-loop appended) ----------------
// Partitioned by dst range into 8 block-groups (~XCDs): scatter targets stay in
// one XCD's L2 (fixes r10's 16x write amplification). csr_src stores PRE-SCALED
// element offsets (src << 7) so the agg gather address is base+off.
__global__ void fill_part(const int* __restrict__ srcp, const int* __restrict__ dstp,
                          const int* __restrict__ rowptr, int* __restrict__ cur,
                          int* __restrict__ csr_src, int E, int N, int nblk) {
  int grp = blockIdx.x & 7;
  int gb = blockIdx.x >> 3;
  int gn = nblk >> 3;
  int lo = (int)(((long long)N * grp) >> 3);
  int hi = (int)(((long long)N * (grp + 1)) >> 3);
  for (int e = gb * blockDim.x + threadIdx.x; e < E; e += gn * blockDim.x) {
    int d = dstp[e];
    if (d >= lo && d < hi) {
      int pos = atomicAdd(&cur[d], 1);
      csr_src[rowptr[d] + pos] = srcp[e] << 7;   // pre-scaled element offset
    }
  }
}

__global__ __launch_bounds__(1024)
void scan_blocks(const int* __restrict__ cnt, int* __restrict__ tscan,
                 int* __restrict__ bsum, int n) {
  __shared__ int sh[1024];
  int t = threadIdx.x;
  int i = blockIdx.x * 1024 + t;
  sh[t] = (i < n) ? cnt[i] + 1 : 0;
  __syncthreads();
  for (int off = 1; off < 1024; off <<= 1) {
    int u = (t >= off) ? sh[t - off] : 0;
    __syncthreads();
    sh[t] += u;
    __syncthreads();
  }
  if (i < n) tscan[i] = sh[t];
  if (t == 1023) bsum[blockIdx.x] = sh[1023];
}

__global__ __launch_bounds__(1024)
void scan_final(int* __restrict__ cnt, const int* __restrict__ tscan,
                const int* __restrict__ bsum, int* __restrict__ rowptr,
                int* __restrict__ csr_src, int n, int nb) {
  __shared__ int sh[1024];
  int t = threadIdx.x;
  sh[t] = (t < nb) ? bsum[t] : 0;
  __syncthreads();
  for (int off = 1; off < 1024; off <<= 1) {
    int u = (t >= off) ? sh[t - off] : 0;
    __syncthreads();
    sh[t] += u;
    __syncthreads();
  }
  int i = blockIdx.x * 1024 + t;
  if (i < n) {
    int bpref = (blockIdx.x == 0) ? 0 : sh[blockIdx.x - 1];
    int incl = bpref + tscan[i];
    rowptr[i] = incl - (cnt[i] + 1);
    csr_src[incl - 1] = i << 7;           // self-loop (pre-scaled)
    cnt[i] = 0;                           // becomes `cur` for fill_part
  }
  if (blockIdx.x == nb - 1 && t == 0) rowptr[n] = sh[nb - 1];
}

// ------- fused: weight-pack + x-cast + partitioned edge count (one launch) -------
// Blocks [0,64): pack 8 weight matrices into MFMA fragments (bf16 hi|lo).
// Blocks [64, 64+splitb): x -> bf16 trunk.
// Blocks [64+splitb, ...): dst-range-partitioned count (8 groups ~ XCDs).
struct PackArgs {
  const float* w[8];
  ushort* o[8];
  int nout[8];
};
__global__ __launch_bounds__(256)
void pack_split_count(PackArgs pa, const float* __restrict__ x,
                      ushort* __restrict__ xhi, int nx,
                      const int* __restrict__ dstp, int* __restrict__ cnt,
                      int E, int N, int splitb, int cntb) {
  if (blockIdx.x < 64) {
    int wsel = blockIdx.x >> 3;
    int sub = blockIdx.x & 7;
    const float* W = pa.w[wsel];
    ushort* pk = pa.o[wsel];
    int NOUT = pa.nout[wsel];
    int NT = NOUT / 16;
    int total = NT * 4 * 64;
    int t = sub * 256 + threadIdx.x;
    if (t >= total) return;
    int lane = t & 63;
    int ks = (t >> 6) & 3;
    int nt = t >> 8;
    int col = nt * 16 + (lane & 15);
    int k0 = ks * 32 + (lane >> 4) * 8;
    ushort h[8], l[8];
#pragma unroll
    for (int j = 0; j < 8; ++j) {
      float v = W[(size_t)(k0 + j) * NOUT + col];
      h[j] = f2bf(v);
      l[j] = f2bf(v - bf2f(h[j]));
    }
    size_t fb = ((size_t)(nt * 4 + ks) * 64 + lane) * 8;
    size_t fragsz = (size_t)total * 8;
#pragma unroll
    for (int j = 0; j < 8; ++j) { pk[fb + j] = h[j]; pk[fragsz + fb + j] = l[j]; }
  } else if (blockIdx.x < 64 + splitb) {
    int i = ((blockIdx.x - 64) * 256 + threadIdx.x) * 4;
    if (i >= nx) return;
    float4 v = *(const float4*)(x + i);
    *(ushort4*)(xhi + i) = make_ushort4(f2bf(v.x), f2bf(v.y), f2bf(v.z), f2bf(v.w));
  } else {
    int b = blockIdx.x - 64 - splitb;
    int grp = b & 7;
    int gb = b >> 3;
    int gn = cntb >> 3;
    int lo = (int)(((long long)N * grp) >> 3);
    int hi = (int)(((long long)N * (grp + 1)) >> 3);
    for (int e = gb * blockDim.x + threadIdx.x; e < E; e += gn * blockDim.x) {
      int d = dstp[e];
      if (d >= lo && d < hi) atomicAdd(&cnt[d], 1);
    }
  }
}

// ---------- Fused triple MFMA GEMM (one-sided bf16x2): Cp = Ah @ (Whi+Wlo) + bp ----------
// 64 rows/block, 512 thr (r17 shape — validated optimum; 128-row variant
// regressed via occupancy loss in r18).
__global__ __launch_bounds__(512)
void gemm3_mfma(const ushort* __restrict__ Ah,
                const ushort* __restrict__ W0, const ushort* __restrict__ W1,
                const ushort* __restrict__ W2,
                const float* __restrict__ b0, const float* __restrict__ b1,
                const float* __restrict__ b2,
                ushort* __restrict__ C0b, ushort* __restrict__ C1b,
                ushort* __restrict__ C2b, int M) {
  int tid = threadIdx.x;
  int w = tid >> 6, lane = tid & 63;
  int l15 = lane & 15, lh = lane >> 4;
  int row0 = blockIdx.x * 64;

  const ushort* Wp[3] = {W0, W1, W2};

  int arow[4];
#pragma unroll
  for (int mt = 0; mt < 4; ++mt) { int rr = row0 + mt * 16 + l15; arow[mt] = rr < M ? rr : M - 1; }

  float4v acc[3][4];
#pragma unroll
  for (int p = 0; p < 3; ++p)
#pragma unroll
    for (int mt = 0; mt < 4; ++mt) {
      acc[p][mt][0] = 0.f; acc[p][mt][1] = 0.f; acc[p][mt][2] = 0.f; acc[p][mt][3] = 0.f;
    }

  const size_t fragsz = (size_t)8 * 4 * 64 * 8;  // NT=8
#pragma unroll 2
  for (int ks = 0; ks < 4; ++ks) {
    short8v bh[3], bl[3];
    size_t fb = ((size_t)(w * 4 + ks) * 64 + lane) * 8;
#pragma unroll
    for (int p = 0; p < 3; ++p) {
      bh[p] = *(const short8v*)(Wp[p] + fb);
      bl[p] = *(const short8v*)(Wp[p] + fragsz + fb);
    }
#pragma unroll
    for (int mt = 0; mt < 4; ++mt) {
      size_t ao = (size_t)arow[mt] * 128 + ks * 32 + lh * 8;
      short8v ah = *(const short8v*)(Ah + ao);
#pragma unroll
      for (int p = 0; p < 3; ++p) {
        acc[p][mt] = __builtin_amdgcn_mfma_f32_16x16x32_bf16(ah, bh[p], acc[p][mt], 0, 0, 0);
        acc[p][mt] = __builtin_amdgcn_mfma_f32_16x16x32_bf16(ah, bl[p], acc[p][mt], 0, 0, 0);
      }
    }
  }

  int col = w * 16 + l15;
  float bb0 = b0[col], bb1 = b1[col], bb2 = b2[col];
#pragma unroll
  for (int mt = 0; mt < 4; ++mt) {
#pragma unroll
    for (int r = 0; r < 4; ++r) {
      int rr = row0 + mt * 16 + lh * 4 + r;
      if (rr < M) {
        C0b[(size_t)rr * 128 + col] = f2bf(acc[0][mt][r] + bb0);
        C1b[(size_t)rr * 128 + col] = f2bf(acc[1][mt][r] + bb1);
        C2b[(size_t)rr * 128 + col] = f2bf(acc[2][mt][r] + bb2);
      }
    }
  }
}

// ---------- Fused MLP head: out = relu(Ah@W1+b1) @ W2 + b2 ----------
__global__ __launch_bounds__(256)
void mlp_fused(const ushort* __restrict__ Ah,
               const ushort* __restrict__ W1pk, const float* __restrict__ b1,
               const ushort* __restrict__ W2pk, const float* __restrict__ b2,
               float* __restrict__ out, int M) {
  __shared__ ushort m1[2][16][64][8];   // [hi/lo][k>>3][row][k&7]
  int tid = threadIdx.x;
  int w = tid >> 6, lane = tid & 63;
  int l15 = lane & 15, lh = lane >> 4;
  int row0 = blockIdx.x * 64;

  int arow[4];
#pragma unroll
  for (int mt = 0; mt < 4; ++mt) { int rr = row0 + mt * 16 + l15; arow[mt] = rr < M ? rr : M - 1; }

  float4v acc1[4][2];
#pragma unroll
  for (int mt = 0; mt < 4; ++mt)
#pragma unroll
    for (int j = 0; j < 2; ++j) {
      acc1[mt][j][0] = 0.f; acc1[mt][j][1] = 0.f; acc1[mt][j][2] = 0.f; acc1[mt][j][3] = 0.f;
    }
  const size_t fragsz1 = (size_t)8 * 4 * 64 * 8;
#pragma unroll 2
  for (int ks = 0; ks < 4; ++ks) {
    short8v bh[2], bl[2];
#pragma unroll
    for (int nt2 = 0; nt2 < 2; ++nt2) {
      size_t fb = ((size_t)((w * 2 + nt2) * 4 + ks) * 64 + lane) * 8;
      bh[nt2] = *(const short8v*)(W1pk + fb);
      bl[nt2] = *(const short8v*)(W1pk + fragsz1 + fb);
    }
#pragma unroll
    for (int mt = 0; mt < 4; ++mt) {
      size_t ao = (size_t)arow[mt] * 128 + ks * 32 + lh * 8;
      short8v ah = *(const short8v*)(Ah + ao);
#pragma unroll
      for (int nt2 = 0; nt2 < 2; ++nt2) {
        acc1[mt][nt2] = __builtin_amdgcn_mfma_f32_16x16x32_bf16(ah, bh[nt2], acc1[mt][nt2], 0, 0, 0);
        acc1[mt][nt2] = __builtin_amdgcn_mfma_f32_16x16x32_bf16(ah, bl[nt2], acc1[mt][nt2], 0, 0, 0);
      }
    }
  }
#pragma unroll
  for (int nt2 = 0; nt2 < 2; ++nt2) {
    int col = (w * 2 + nt2) * 16 + l15;
    float bb = b1[col];
    int kf = col >> 3, kr = col & 7;
#pragma unroll
    for (int mt = 0; mt < 4; ++mt) {
#pragma unroll
      for (int r = 0; r < 4; ++r) {
        int row = mt * 16 + lh * 4 + r;
        float v = fmaxf(acc1[mt][nt2][r] + bb, 0.f);
        ushort h = f2bf(v);
        m1[0][kf][row][kr] = h;
        m1[1][kf][row][kr] = f2bf(v - bf2f(h));
      }
    }
  }
  __syncthreads();

  float4v acc2[4];
#pragma unroll
  for (int mt = 0; mt < 4; ++mt) {
    acc2[mt][0] = 0.f; acc2[mt][1] = 0.f; acc2[mt][2] = 0.f; acc2[mt][3] = 0.f;
  }
  const size_t fragsz2 = (size_t)4 * 4 * 64 * 8;
#pragma unroll 2
  for (int ks = 0; ks < 4; ++ks) {
    size_t fb = ((size_t)(w * 4 + ks) * 64 + lane) * 8;
    short8v bh = *(const short8v*)(W2pk + fb);
    short8v bl = *(const short8v*)(W2pk + fragsz2 + fb);
#pragma unroll
    for (int mt = 0; mt < 4; ++mt) {
      int row = mt * 16 + l15;
      short8v ah = *(const short8v*)&m1[0][ks * 4 + lh][row][0];
      short8v al = *(const short8v*)&m1[1][ks * 4 + lh][row][0];
      acc2[mt] = __builtin_amdgcn_mfma_f32_16x16x32_bf16(ah, bh, acc2[mt], 0, 0, 0);
      acc2[mt] = __builtin_amdgcn_mfma_f32_16x16x32_bf16(ah, bl, acc2[mt], 0, 0, 0);
      acc2[mt] = __builtin_amdgcn_mfma_f32_16x16x32_bf16(al, bh, acc2[mt], 0, 0, 0);
    }
  }
  int col = w * 16 + l15;
  float bb = b2[col];
#pragma unroll
  for (int mt = 0; mt < 4; ++mt) {
#pragma unroll
    for (int r = 0; r < 4; ++r) {
      int rr = row0 + mt * 16 + lh * 4 + r;
      if (rr < M) out[(size_t)rr * 64 + col] = acc2[mt][r] + bb;
    }
  }
}

// ---------- GATv2 aggregation: pk-fp32, 4 edges/half ----------
template<int H>
__global__ __launch_bounds__(256)
void gat_agg(const ushort* __restrict__ xlb, const ushort* __restrict__ xrb,
             const ushort* __restrict__ skb, const float* __restrict__ att,
             const float* __restrict__ gbias, const int* __restrict__ rowptr,
             const int* __restrict__ csr_src, ushort* __restrict__ outhi,
             int n, int relu) {
  constexpr int GL = (128 / H) / 4;  // lanes per head group: H=4 -> 8, H=1 -> 32
  int wid = blockIdx.x * (blockDim.x >> 6) + (threadIdx.x >> 6);
  if (wid >= n) return;
  int lane = threadIdx.x & 63;
  int half = lane >> 5;
  int sub = lane & 31;
  size_t base = (size_t)wid * 128 + sub * 4;
  const ushort* xl_l = xlb + sub * 4;   // per-lane base; gather = xl_l + off
  uint2 ur = *(const uint2*)(xrb + base);
  float2v xr01 = {ubf(ur.x, 0), ubf(ur.x, 1)};
  float2v xr23 = {ubf(ur.y, 0), ubf(ur.y, 1)};
  float4 avf = *(const float4*)(att + sub * 4);
  float2v av01 = {avf.x, avf.y};
  float2v av23 = {avf.z, avf.w};
  float2v acc01 = {0.f, 0.f}, acc23 = {0.f, 0.f};
  float denom = 0.f;
  int e0 = rowptr[wid], e1 = rowptr[wid + 1];

  int idx = e0 + half;
  for (; idx + 6 < e1; idx += 8) {
    int o0 = csr_src[idx], o1 = csr_src[idx + 2], o2 = csr_src[idx + 4], o3 = csr_src[idx + 6];
    uint2 u0 = *(const uint2*)(xl_l + o0);
    uint2 u1 = *(const uint2*)(xl_l + o1);
    uint2 u2 = *(const uint2*)(xl_l + o2);
    uint2 u3 = *(const uint2*)(xl_l + o3);
    float2v a01 = {ubf(u0.x, 0), ubf(u0.x, 1)}, a23 = {ubf(u0.y, 0), ubf(u0.y, 1)};
    float2v b01 = {ubf(u1.x, 0), ubf(u1.x, 1)}, b23 = {ubf(u1.y, 0), ubf(u1.y, 1)};
    float2v c01 = {ubf(u2.x, 0), ubf(u2.x, 1)}, c23 = {ubf(u2.y, 0), ubf(u2.y, 1)};
    float2v d01 = {ubf(u3.x, 0), ubf(u3.x, 1)}, d23 = {ubf(u3.y, 0), ubf(u3.y, 1)};
    float2v t01, t23, l01, l23, pp;
    t01 = a01 + xr01; t23 = a23 + xr23;
    l01 = __builtin_elementwise_max(t01, t01 * 0.2f);
    l23 = __builtin_elementwise_max(t23, t23 * 0.2f);
    pp = __builtin_elementwise_fma(l23, av23, l01 * av01);
    float p0 = pp[0] + pp[1];
    t01 = b01 + xr01; t23 = b23 + xr23;
    l01 = __builtin_elementwise_max(t01, t01 * 0.2f);
    l23 = __builtin_elementwise_max(t23, t23 * 0.2f);
    pp = __builtin_elementwise_fma(l23, av23, l01 * av01);
    float p1 = pp[0] + pp[1];
    t01 = c01 + xr01; t23 = c23 + xr23;
    l01 = __builtin_elementwise_max(t01, t01 * 0.2f);
    l23 = __builtin_elementwise_max(t23, t23 * 0.2f);
    pp = __builtin_elementwise_fma(l23, av23, l01 * av01);
    float p2 = pp[0] + pp[1];
    t01 = d01 + xr01; t23 = d23 + xr23;
    l01 = __builtin_elementwise_max(t01, t01 * 0.2f);
    l23 = __builtin_elementwise_max(t23, t23 * 0.2f);
    pp = __builtin_elementwise_fma(l23, av23, l01 * av01);
    float p3 = pp[0] + pp[1];
#pragma unroll
    for (int o = 1; o < GL; o <<= 1) {
      p0 += __shfl_xor(p0, o, 64);
      p1 += __shfl_xor(p1, o, 64);
      p2 += __shfl_xor(p2, o, 64);
      p3 += __shfl_xor(p3, o, 64);
    }
    float w0 = __expf(p0), w1 = __expf(p1), w2 = __expf(p2), w3 = __expf(p3);
    denom += (w0 + w1) + (w2 + w3);
    float2v w0v = {w0, w0}, w1v = {w1, w1}, w2v = {w2, w2}, w3v = {w3, w3};
    acc01 = __builtin_elementwise_fma(w0v, a01, acc01);
    acc23 = __builtin_elementwise_fma(w0v, a23, acc23);
    acc01 = __builtin_elementwise_fma(w1v, b01, acc01);
    acc23 = __builtin_elementwise_fma(w1v, b23, acc23);
    acc01 = __builtin_elementwise_fma(w2v, c01, acc01);
    acc23 = __builtin_elementwise_fma(w2v, c23, acc23);
    acc01 = __builtin_elementwise_fma(w3v, d01, acc01);
    acc23 = __builtin_elementwise_fma(w3v, d23, acc23);
  }
  for (; idx < e1; idx += 2) {
    int o0 = csr_src[idx];
    uint2 u0 = *(const uint2*)(xl_l + o0);
    float2v a01 = {ubf(u0.x, 0), ubf(u0.x, 1)}, a23 = {ubf(u0.y, 0), ubf(u0.y, 1)};
    float2v t01 = a01 + xr01, t23 = a23 + xr23;
    float2v l01 = __builtin_elementwise_max(t01, t01 * 0.2f);
    float2v l23 = __builtin_elementwise_max(t23, t23 * 0.2f);
    float2v pp = __builtin_elementwise_fma(l23, av23, l01 * av01);
    float p0 = pp[0] + pp[1];
#pragma unroll
    for (int o = 1; o < GL; o <<= 1) p0 += __shfl_xor(p0, o, 64);
    float w0 = __expf(p0);
    denom += w0;
    float2v w0v = {w0, w0};
    acc01 = __builtin_elementwise_fma(w0v, a01, acc01);
    acc23 = __builtin_elementwise_fma(w0v, a23, acc23);
  }

  float ax = acc01[0], ay = acc01[1], az = acc23[0], aw = acc23[1];
  ax += __shfl_xor(ax, 32, 64);
  ay += __shfl_xor(ay, 32, 64);
  az += __shfl_xor(az, 32, 64);
  aw += __shfl_xor(aw, 32, 64);
  denom += __shfl_xor(denom, 32, 64);

  if (half == 0) {
    float inv = 1.f / denom;
    uint2 us = *(const uint2*)(skb + base);
    float4 sk;
    sk.x = ubf(us.x, 0); sk.y = ubf(us.x, 1);
    sk.z = ubf(us.y, 0); sk.w = ubf(us.y, 1);
    float4 gb = *(const float4*)(gbias + sub * 4);
    float o0 = ax * inv + gb.x + sk.x;
    float o1 = ay * inv + gb.y + sk.y;
    float o2 = az * inv + gb.z + sk.z;
    float o3 = aw * inv + gb.w + sk.w;
    if (relu) {
      o0 = fmaxf(o0, 0.f); o1 = fmaxf(o1, 0.f);
      o2 = fmaxf(o2, 0.f); o3 = fmaxf(o3, 0.f);
    }
    *(ushort4*)(outhi + base) = make_ushort4(f2bf(o0), f2bf(o1), f2bf(o2), f2bf(o3));
  }
}

extern "C" void kernel_launch(void* const* d_in, const int* in_sizes, int n_in,
                              void* d_out, int out_size, void* d_ws, size_t ws_size,
                              hipStream_t stream) {
  const float* x       = (const float*)d_in[0];
  const int* ei        = (const int*)d_in[1];
  const float* Wl1     = (const float*)d_in[2];
  const float* bl1     = (const float*)d_in[3];
  const float* Wr1     = (const float*)d_in[4];
  const float* br1     = (const float*)d_in[5];
  const float* att1    = (const float*)d_in[6];
  const float* b1      = (const float*)d_in[7];
  const float* Wl2     = (const float*)d_in[8];
  const float* bl2     = (const float*)d_in[9];
  const float* Wr2     = (const float*)d_in[10];
  const float* br2     = (const float*)d_in[11];
  const float* att2    = (const float*)d_in[12];
  const float* b2      = (const float*)d_in[13];
  const float* skip1_w = (const float*)d_in[14];
  const float* skip1_b = (const float*)d_in[15];
  const float* skip2_w = (const float*)d_in[16];
  const float* skip2_b = (const float*)d_in[17];
  const float* mlp1_w  = (const float*)d_in[18];
  const float* mlp1_b  = (const float*)d_in[19];
  const float* mlp2_w  = (const float*)d_in[20];
  const float* mlp2_b  = (const float*)d_in[21];

  const int N = in_sizes[0] / 128;
  const int E = in_sizes[1] / 2;
  float* out = (float*)d_out;

  char* ws = (char*)d_ws;
  size_t off = 0;
  auto alloc = [&](size_t bytes) -> void* {
    void* p = ws + off;
    off = (off + bytes + 255) & ~(size_t)255;
    return p;
  };
  int* rowptr  = (int*)alloc((size_t)(N + 1) * sizeof(int));
  int* cnt     = (int*)alloc((size_t)N * sizeof(int));
  int* tscan   = (int*)alloc((size_t)N * sizeof(int));
  int* bsum    = (int*)alloc((size_t)1024 * sizeof(int));
  int* csr_src = (int*)alloc((size_t)(E + N) * sizeof(int));
  ushort* wpk[8];
  for (int i = 0; i < 8; ++i) wpk[i] = (ushort*)alloc(128 * 128 * 2 * sizeof(ushort));
  ushort* p0hi = (ushort*)alloc((size_t)N * 128 * sizeof(ushort));
  ushort* xlb  = (ushort*)alloc((size_t)N * 128 * sizeof(ushort));
  ushort* xrb  = (ushort*)alloc((size_t)N * 128 * sizeof(ushort));
  ushort* skb  = (ushort*)alloc((size_t)N * 128 * sizeof(ushort));

  const int* srcp = ei;
  const int* dstp = ei + E;

  const int ggrid  = (N + 63) / 64;
  const int agrid  = (N + 3) / 4;
  const int nb = (N + 1023) / 1024;
  const int PARTB = 2048;

  // Weight packs + x bf16-cast + partitioned count, all in one launch
  PackArgs pa;
  pa.w[0] = Wl1;    pa.o[0] = wpk[0]; pa.nout[0] = 128;
  pa.w[1] = Wr1;    pa.o[1] = wpk[1]; pa.nout[1] = 128;
  pa.w[2] = skip1_w;pa.o[2] = wpk[2]; pa.nout[2] = 128;
  pa.w[3] = Wl2;    pa.o[3] = wpk[3]; pa.nout[3] = 128;
  pa.w[4] = Wr2;    pa.o[4] = wpk[4]; pa.nout[4] = 128;
  pa.w[5] = skip2_w;pa.o[5] = wpk[5]; pa.nout[5] = 128;
  pa.w[6] = mlp1_w; pa.o[6] = wpk[6]; pa.nout[6] = 128;
  pa.w[7] = mlp2_w; pa.o[7] = wpk[7]; pa.nout[7] = 64;
  const int splitb = (N * 128 / 4 + 255) / 256;

  hipMemsetAsync(cnt, 0, (size_t)N * sizeof(int), stream);
  pack_split_count<<<64 + splitb + PARTB, 256, 0, stream>>>(
      pa, x, p0hi, N * 128, dstp, cnt, E, N, splitb, PARTB);
  scan_blocks<<<nb, 1024, 0, stream>>>(cnt, tscan, bsum, N);
  scan_final<<<nb, 1024, 0, stream>>>(cnt, tscan, bsum, rowptr, csr_src, N, nb);
  fill_part<<<PARTB, 256, 0, stream>>>(srcp, dstp, rowptr, cnt, csr_src, E, N, PARTB);

  // ---- Layer 1: fused {xl1, xr1, skip1} GEMM, then agg ----
  gemm3_mfma<<<ggrid, 512, 0, stream>>>(p0hi, wpk[0], wpk[1], wpk[2],
                                        bl1, br1, skip1_b, xlb, xrb, skb, N);
  gat_agg<4><<<agrid, 256, 0, stream>>>(xlb, xrb, skb, att1, b1,
                                        rowptr, csr_src, p0hi, N, 1);

  // ---- Layer 2: fused {xl2, xr2, skip2} GEMM, then agg ----
  gemm3_mfma<<<ggrid, 512, 0, stream>>>(p0hi, wpk[3], wpk[4], wpk[5],
                                        bl2, br2, skip2_b, xlb, xrb, skb, N);
  gat_agg<1><<<agrid, 256, 0, stream>>>(xlb, xrb, skb, att2, b2,
                                        rowptr, csr_src, p0hi, N, 0);

  // ---- Fused MLP head ----
  mlp_fused<<<ggrid, 256, 0, stream>>>(p0hi, wpk[6], mlp1_b, wpk[7], mlp2_b, out, N);
}